// Round 8
// baseline (135.261 us; speedup 1.0000x reference)
//
#include <hip/hip_runtime.h>

// Reference-exact fp32 d2: no FMA contraction. d2 = (sqn+sqm) + dot' with
// dot' built from (-2x) pre-scaled m-points is bit-identical to the ref's
// (sqn+sqm) - 2*dot (power-of-2 scaling / negation commute with rounding).
// Self-distance: dt(n,n) = -2*sq_n exactly, so d2(n,n) == +0.0 exactly.
//
// Comparison domains (exact, not dataset-dependent):
//  argmax: signed-int compare on float bits. Positive floats are
//    order-isomorphic to their bit patterns; negative d2 maps to the deep-
//    negative int range and can never beat a positive (ref clamps them to
//    dist 0, which also loses to any positive distance).
//  argmin: unsigned compare on (bits - 1). d2=+0.0 -> 0xFFFFFFFF (never wins,
//    = ref's dist==0 mask); negative/-0.0 -> >=0x7FFFFFFF (never wins, = ref
//    clamp->0->masked); positive ordering and exact ties preserved.
#pragma clang fp contract(off)

typedef float v2f __attribute__((ext_vector_type(2)));

#define NBATCH 256   // B*L
#define NPTS   512   // points per batch
#define JDIM   128   // logit dim
#define NPAIR  (NBATCH * NPTS)   // 131072

// ---------------- K1: per-point argmax / masked-argmin of d2 ----------------
// Grid 1024 = 4 blocks/batch (128 points each). Block 512 thr, 40 KB LDS.
// Thread t: point-group g = t&31 (4 pts), m-subrange s = t>>5 (32 m's).
// d2 math in packed fp32 (v_pk_mul/add), compares in int domain.
__global__ __launch_bounds__(512) void argmm_kernel(
    const float* __restrict__ xyz,   // [NBATCH, NPTS, 3]
    int* __restrict__ pmax,          // [NBATCH*NPTS]
    int* __restrict__ pmin)          // [NBATCH*NPTS]
{
    __shared__ float4 xyzS[NPTS];            // scaled (-2x,-2y,-2z, sq) : 8 KB
    __shared__ int mv[16][128];  __shared__ int mi[16][128];     // 16 KB
    __shared__ unsigned nv[16][128];  __shared__ int ni[16][128];// 16 KB

    const int t  = threadIdx.x;
    const int bl = blockIdx.x >> 2;
    const int qq = blockIdx.x & 3;           // point-quarter of this block
    const float* xp = xyz + (size_t)bl * NPTS * 3;

    // stage all 512 points, scaled; sq computed in ref order from raw values
    {
        float x = xp[3 * t], y = xp[3 * t + 1], z = xp[3 * t + 2];
        float sq = (x * x + y * y) + z * z;  // matches np.sum(x*x,-1)
        xyzS[t] = make_float4(-2.0f * x, -2.0f * y, -2.0f * z, sq);
    }

    // own 4 points raw from global, packed into v2f pairs
    const int g = t & 31, s = t >> 5;
    const int pbase = qq * 128 + g * 4;
    v2f ox2[2], oy2[2], oz2[2], oq2[2];
    {
        const float4* own = (const float4*)(xp + 3 * pbase);
        float4 o0 = own[0], o1 = own[1], o2 = own[2];
        ox2[0] = (v2f){o0.x, o0.w};  oy2[0] = (v2f){o0.y, o1.x};  oz2[0] = (v2f){o0.z, o1.y};
        ox2[1] = (v2f){o1.z, o2.y};  oy2[1] = (v2f){o1.w, o2.z};  oz2[1] = (v2f){o2.x, o2.w};
        #pragma unroll
        for (int j = 0; j < 2; ++j)
            oq2[j] = (ox2[j] * ox2[j] + oy2[j] * oy2[j]) + oz2[j] * oz2[j];
    }
    __syncthreads();

    const int mbase = s * 32;
    int bmaxi[4], ima[4], imi[4]; unsigned bminu[4];
    #pragma unroll
    for (int k = 0; k < 4; ++k) {
        bmaxi[k] = 0x80000000;               // INT_MIN
        bminu[k] = 0xFFFFFFFFu;
        ima[k] = mbase; imi[k] = mbase;
    }

    #pragma unroll 8
    for (int mm = 0; mm < 32; ++mm) {
        int m = mbase + mm;
        float4 qv = xyzS[m];                 // 2 addrs/wave -> broadcast
        v2f qx = (v2f){qv.x, qv.x}, qy = (v2f){qv.y, qv.y};
        v2f qz = (v2f){qv.z, qv.z}, qw = (v2f){qv.w, qv.w};
        #pragma unroll
        for (int j = 0; j < 2; ++j) {
            v2f dt = (ox2[j] * qx + oy2[j] * qy) + oz2[j] * qz;  // == -2*dot
            v2f d2 = (oq2[j] + qw) + dt;     // bits == ref d2 (pre-clamp)
            int b0 = __float_as_int(d2.x);
            int b1 = __float_as_int(d2.y);
            const int k0 = 2 * j, k1 = 2 * j + 1;

            bool g0 = b0 > bmaxi[k0];
            ima[k0] = g0 ? m : ima[k0];  bmaxi[k0] = g0 ? b0 : bmaxi[k0];
            unsigned u0 = (unsigned)b0 - 1u;
            bool l0 = u0 < bminu[k0];
            imi[k0] = l0 ? m : imi[k0];  bminu[k0] = l0 ? u0 : bminu[k0];

            bool g1 = b1 > bmaxi[k1];
            ima[k1] = g1 ? m : ima[k1];  bmaxi[k1] = g1 ? b1 : bmaxi[k1];
            unsigned u1 = (unsigned)b1 - 1u;
            bool l1 = u1 < bminu[k1];
            imi[k1] = l1 ? m : imi[k1];  bminu[k1] = l1 ? u1 : bminu[k1];
        }
    }

    #pragma unroll
    for (int k = 0; k < 4; ++k) {
        int pt = g * 4 + k;
        mv[s][pt] = bmaxi[k];  mi[s][pt] = ima[k];
        nv[s][pt] = bminu[k];  ni[s][pt] = imi[k];
    }
    __syncthreads();

    // merge 16 ascending-m subranges; strict compare keeps lowest m-range on
    // exact ties -> first-occurrence. 128 threads max, 128 threads min.
    if (t < 256) {
        const int pt = t & 127;
        const int out_idx = bl * NPTS + qq * 128 + pt;
        if (t < 128) {
            int bv = mv[0][pt]; int bi = mi[0][pt];
            #pragma unroll
            for (int ss = 1; ss < 16; ++ss) {
                int v = mv[ss][pt]; int i = mi[ss][pt];
                bool w = v > bv; bi = w ? i : bi; bv = w ? v : bv;
            }
            pmax[out_idx] = bi;
        } else {
            unsigned sv = nv[0][pt]; int si = ni[0][pt];
            #pragma unroll
            for (int ss = 1; ss < 16; ++ss) {
                unsigned u = nv[ss][pt]; int j = ni[ss][pt];
                bool x = u < sv; si = x ? j : si; sv = x ? u : sv;
            }
            pmin[out_idx] = si;
        }
    }
}

// ---------------- K2: sim gathers + final mean via atomics ------------------
// Grid 2048 = 256 batches x 8 chunks of 16 ypred rows. Block 512 thr: thread
// t owns point n=t; reads a once, gathers both partners from the LDS tile.
// ypred read exactly once from HBM chip-wide -> streaming-bound.
__global__ __launch_bounds__(512) void sim_kernel(
    const float* __restrict__ ypred,   // [NBATCH, JDIM, NPTS]
    const int* __restrict__ pmax,
    const int* __restrict__ pmin,
    float* __restrict__ out)           // scalar accumulator (pre-zeroed)
{
    __shared__ float L[16 * NPTS];     // 32 KB tile
    __shared__ float wred[8];

    const int t  = threadIdx.x;
    const int bl = blockIdx.x >> 3;
    const int c  = blockIdx.x & 7;     // j-chunk

    // partner indices: issue early, land under the staging loads
    const int pma = pmax[bl * NPTS + t];
    const int pmi = pmin[bl * NPTS + t];

    const float4* src = (const float4*)(ypred + (size_t)bl * JDIM * NPTS
                                              + (size_t)c * 16 * NPTS);
    float4 v0 = src[t], v1 = src[512 + t], v2 = src[1024 + t], v3 = src[1536 + t];
    float4* dst = (float4*)L;
    dst[t] = v0;  dst[512 + t] = v1;  dst[1024 + t] = v2;  dst[1536 + t] = v3;
    __syncthreads();

    float accP = 0.0f, accM = 0.0f;
    #pragma unroll
    for (int r = 0; r < 16; ++r) {
        float a  = L[r * NPTS + t];      // stride-1, conflict-free
        float b  = L[r * NPTS + pma];    // random gather, ~2-way avg
        float cm = L[r * NPTS + pmi];
        accP = fmaf(a, b, accP);
        accM = fmaf(a, cm, accM);
    }

    float d = accP - accM;
    #pragma unroll
    for (int off = 32; off > 0; off >>= 1)
        d += __shfl_down(d, off);
    if ((t & 63) == 0) wred[t >> 6] = d;
    __syncthreads();
    if (t == 0) {
        float ssum = 0.0f;
        #pragma unroll
        for (int w = 0; w < 8; ++w) ssum += wred[w];
        atomicAdd(out, ssum * (1.0f / (float)NPAIR));
    }
}

extern "C" void kernel_launch(void* const* d_in, const int* in_sizes, int n_in,
                              void* d_out, int out_size, void* d_ws, size_t ws_size,
                              hipStream_t stream) {
    const float* ypred = (const float*)d_in[0];   // [8,32,128,512] f32
    const float* xyz   = (const float*)d_in[1];   // [8,32,512,3]  f32

    // ws: pmax[131072] ints, pmin[131072] ints (1 MB)
    int* pmax = (int*)d_ws;
    int* pmin = pmax + NPAIR;
    float* out = (float*)d_out;

    hipMemsetAsync(out, 0, sizeof(float), stream);   // d_out is poisoned 0xAA
    argmm_kernel<<<4 * NBATCH, 512, 0, stream>>>(xyz, pmax, pmin);
    sim_kernel<<<8 * NBATCH, 512, 0, stream>>>(ypred, pmax, pmin, out);
}

// Round 9
// 117.529 us; speedup vs baseline: 1.1509x; 1.1509x over previous
//
#include <hip/hip_runtime.h>

// Reference-exact fp32 d2: no FMA contraction. d2 = (sqn+sqm) + dot' with
// dot' built from (-2x) pre-scaled m-points is bit-identical to the ref's
// (sqn+sqm) - 2*dot (power-of-2 scaling / negation commute with rounding).
// Self-distance: dt(n,n) = -2*sq_n exactly, so d2(n,n) == +0.0 exactly.
//
// Comparison domains (exact, dataset-independent):
//  argmax: signed-int compare on d2 bits. Positive floats are order-
//    isomorphic to their bit patterns; rounding-negative d2 maps deep
//    negative and never beats a positive (ref clamps them to dist 0, which
//    also loses to any positive distance).
//  argmin: unsigned compare on (bits - 1). d2=+0.0 -> 0xFFFFFFFF (never wins
//    = ref's dist==0 -> 1e6 mask); negative d2 -> >= 0x7FFFFFFF (never wins
//    = ref clamp->0->masked); positive ordering and exact ties preserved.
//  (-0.0 cannot occur: sqn+sqm >= 0 and pos+neg exact cancellation gives +0.0.)
#pragma clang fp contract(off)

#define NBATCH 256   // B*L
#define NPTS   512   // points per batch
#define JDIM   128   // logit dim
#define NPAIR  (NBATCH * NPTS)   // 131072

// ---------------- K1: per-point argmax / masked-argmin of d2 ----------------
// Grid 1024 = 4 blocks/batch (128 points each). Block 512 thr, 40 KB LDS ->
// 4 blocks/CU. Thread t: point-group g = t&31 (4 pts), m-subrange s = t>>5
// (32 m's). One 2-address LDS broadcast read feeds 4 d2's (2-way = free).
__global__ __launch_bounds__(512) void argmm_kernel(
    const float* __restrict__ xyz,   // [NBATCH, NPTS, 3]
    int* __restrict__ pmax,          // [NBATCH*NPTS]
    int* __restrict__ pmin)          // [NBATCH*NPTS]
{
    __shared__ float4 xyzS[NPTS];            // scaled (-2x,-2y,-2z, sq) : 8 KB
    __shared__ int      mv[16][128];  __shared__ int mi[16][128];   // 16 KB
    __shared__ unsigned nv[16][128];  __shared__ int ni[16][128];   // 16 KB

    const int t  = threadIdx.x;
    const int bl = blockIdx.x >> 2;
    const int qq = blockIdx.x & 3;           // point-quarter of this block
    const float* xp = xyz + (size_t)bl * NPTS * 3;

    // stage all 512 points, scaled; sq computed in ref order from raw values
    {
        float x = xp[3 * t], y = xp[3 * t + 1], z = xp[3 * t + 2];
        float sq = (x * x + y * y) + z * z;  // matches np.sum(x*x,-1)
        xyzS[t] = make_float4(-2.0f * x, -2.0f * y, -2.0f * z, sq);
    }

    // own 4 points raw from global: 12 consecutive floats = 3 float4
    const int g = t & 31, s = t >> 5;
    const int pbase = qq * 128 + g * 4;
    float ox[4], oy[4], oz[4], oq[4];
    {
        const float4* own = (const float4*)(xp + 3 * pbase);
        float4 o0 = own[0], o1 = own[1], o2 = own[2];
        ox[0] = o0.x; oy[0] = o0.y; oz[0] = o0.z;
        ox[1] = o0.w; oy[1] = o1.x; oz[1] = o1.y;
        ox[2] = o1.z; oy[2] = o1.w; oz[2] = o2.x;
        ox[3] = o2.y; oy[3] = o2.z; oz[3] = o2.w;
        #pragma unroll
        for (int k = 0; k < 4; ++k)
            oq[k] = (ox[k] * ox[k] + oy[k] * oy[k]) + oz[k] * oz[k];
    }
    __syncthreads();

    const int mbase = s * 32;
    int bmax[4], ima[4], imi[4]; unsigned bmin[4];
    #pragma unroll
    for (int k = 0; k < 4; ++k) {
        bmax[k] = (int)0x80000000;           // INT_MIN
        bmin[k] = 0xFFFFFFFFu;
        ima[k] = mbase; imi[k] = mbase;
    }

    #pragma unroll 8
    for (int mm = 0; mm < 32; ++mm) {
        int m = mbase + mm;
        float4 qv = xyzS[m];                 // 2 addrs/wave -> free broadcast
        #pragma unroll
        for (int k = 0; k < 4; ++k) {
            float dt = (ox[k] * qv.x + oy[k] * qv.y) + oz[k] * qv.z; // == -2*dot
            float d2 = (oq[k] + qv.w) + dt;  // bits == ref d2 (pre-clamp)
            int b = __float_as_int(d2);
            bool gt = b > bmax[k];           // strict -> first occurrence
            ima[k] = gt ? m : ima[k];  bmax[k] = gt ? b : bmax[k];
            unsigned u = (unsigned)b - 1u;   // +0.0 / negatives -> never-wins
            bool lt = u < bmin[k];
            imi[k] = lt ? m : imi[k];  bmin[k] = lt ? u : bmin[k];
        }
    }

    #pragma unroll
    for (int k = 0; k < 4; ++k) {
        int pt = g * 4 + k;
        mv[s][pt] = bmax[k];  mi[s][pt] = ima[k];
        nv[s][pt] = bmin[k];  ni[s][pt] = imi[k];
    }
    __syncthreads();

    // merge 16 ascending-m subranges; strict compare keeps lowest m-range on
    // exact ties -> first-occurrence. 128 threads max, 128 threads min.
    if (t < 256) {
        const int pt = t & 127;
        const int out_idx = bl * NPTS + qq * 128 + pt;
        if (t < 128) {
            int bv = mv[0][pt]; int bi = mi[0][pt];
            #pragma unroll
            for (int ss = 1; ss < 16; ++ss) {
                int v = mv[ss][pt]; int i = mi[ss][pt];
                bool w = v > bv; bi = w ? i : bi; bv = w ? v : bv;
            }
            pmax[out_idx] = bi;
        } else {
            unsigned sv = nv[0][pt]; int si = ni[0][pt];
            #pragma unroll
            for (int ss = 1; ss < 16; ++ss) {
                unsigned u = nv[ss][pt]; int j = ni[ss][pt];
                bool x = u < sv; si = x ? j : si; sv = x ? u : sv;
            }
            pmin[out_idx] = si;
        }
    }
}

// ---------------- K2: sim gathers, j-chunked, one barrier per block --------
// Grid 2048 = 256 batches x 8 chunks of 16 ypred rows. Block 512 thr: thread
// t owns point n=t. Its own a-column comes straight from global into
// registers (16 coalesced b32); LDS holds the tile only for the two random
// partner gathers. ypred read exactly once from HBM chip-wide.
__global__ __launch_bounds__(512) void sim_kernel(
    const float* __restrict__ ypred,   // [NBATCH, JDIM, NPTS]
    const int* __restrict__ pmax,
    const int* __restrict__ pmin,
    float* __restrict__ partials)      // [2048]
{
    __shared__ float L[16 * NPTS];     // 32 KB tile
    __shared__ float wred[8];

    const int t  = threadIdx.x;
    const int bl = blockIdx.x >> 3;
    const int c  = blockIdx.x & 7;     // j-chunk

    // partner indices: issue early, land under the staging loads
    const int pma = pmax[bl * NPTS + t];
    const int pmi = pmin[bl * NPTS + t];

    const float* base = ypred + (size_t)bl * JDIM * NPTS + (size_t)c * 16 * NPTS;
    float a[16];
    #pragma unroll
    for (int r = 0; r < 16; ++r)
        a[r] = base[r * NPTS + t];     // coalesced b32, stays in registers
    #pragma unroll
    for (int r = 0; r < 16; ++r)
        L[r * NPTS + t] = a[r];        // stride-1 writes, conflict-free
    __syncthreads();

    float accP = 0.0f, accM = 0.0f;
    #pragma unroll
    for (int r = 0; r < 16; ++r) {
        float b  = L[r * NPTS + pma];  // random gather, ~2-way avg (free-ish)
        float cm = L[r * NPTS + pmi];
        accP = fmaf(a[r], b,  accP);
        accM = fmaf(a[r], cm, accM);
    }

    float d = accP - accM;
    #pragma unroll
    for (int off = 32; off > 0; off >>= 1)
        d += __shfl_down(d, off);
    if ((t & 63) == 0) wred[t >> 6] = d;
    __syncthreads();
    if (t == 0) {
        float ssum = 0.0f;
        #pragma unroll
        for (int w = 0; w < 8; ++w) ssum += wred[w];
        partials[blockIdx.x] = ssum;
    }
}

// ---------------- K3: final mean over 2048 partials -------------------------
__global__ __launch_bounds__(1024) void reduce_mean_kernel(
    const float* __restrict__ partials, float* __restrict__ out)
{
    const int t = threadIdx.x;
    float v = partials[t] + partials[t + 1024];
    #pragma unroll
    for (int off = 32; off > 0; off >>= 1)
        v += __shfl_down(v, off);

    __shared__ float w[16];
    if ((t & 63) == 0) w[t >> 6] = v;
    __syncthreads();
    if (t == 0) {
        float s = 0.0f;
        #pragma unroll
        for (int i = 0; i < 16; ++i) s += w[i];
        out[0] = s * (1.0f / (float)NPAIR);
    }
}

extern "C" void kernel_launch(void* const* d_in, const int* in_sizes, int n_in,
                              void* d_out, int out_size, void* d_ws, size_t ws_size,
                              hipStream_t stream) {
    const float* ypred = (const float*)d_in[0];   // [8,32,128,512] f32
    const float* xyz   = (const float*)d_in[1];   // [8,32,512,3]  f32

    // ws: pmax[131072] ints, pmin[131072] ints, partials[2048] floats (~1.06 MB)
    int*   pmax     = (int*)d_ws;
    int*   pmin     = pmax + NPAIR;
    float* partials = (float*)(pmin + NPAIR);
    float* out      = (float*)d_out;

    argmm_kernel<<<4 * NBATCH, 512, 0, stream>>>(xyz, pmax, pmin);
    sim_kernel<<<8 * NBATCH, 512, 0, stream>>>(ypred, pmax, pmin, partials);
    reduce_mean_kernel<<<1, 1024, 0, stream>>>(partials, out);
}

// Round 10
// 116.703 us; speedup vs baseline: 1.1590x; 1.0071x over previous
//
#include <hip/hip_runtime.h>

// Reference-exact fp32 d2: no FMA contraction. d2 = (sqn+sqm) + dot' with
// dot' built from (-2x) pre-scaled m-points is bit-identical to the ref's
// (sqn+sqm) - 2*dot (power-of-2 scaling / negation commute with rounding).
// Self-distance: dt(n,n) = -2*sq_n exactly, so d2(n,n) == +0.0 exactly.
// v_pk_mul_f32 / v_pk_add_f32 are per-lane IEEE-identical to the scalar ops,
// so packed evaluation preserves bit-exactness.
//
// Comparison domains (exact, dataset-independent):
//  argmax: signed-int compare on d2 bits (positive floats order-isomorphic
//    to bits; rounding-negative d2 -> deep negative, never beats positive,
//    matching ref clamp-to-0 which also loses to any positive distance).
//  argmin: unsigned compare on (bits - 1): +0.0 -> 0xFFFFFFFF (never wins =
//    ref's dist==0 -> 1e6 mask); negative d2 -> >= 0x7FFFFFFF (never wins =
//    ref clamp->0->masked); positive ordering and exact ties preserved.
#pragma clang fp contract(off)

typedef float v2f __attribute__((ext_vector_type(2)));

#define NBATCH 256   // B*L
#define NPTS   512   // points per batch
#define JDIM   128   // logit dim
#define NPAIR  (NBATCH * NPTS)   // 131072

// ---------------- K1: per-point argmax / masked-argmin of d2 ----------------
// Grid 1024 = 4 blocks/batch (128 points each). Block 512 thr, 32 KB LDS ->
// 4 blocks/CU. Thread t: point-group g = t&31 (4 pts as 2 v2f pairs),
// m-subrange s = t>>5 (32 m's). m-points staged DUPLICATED in LDS
// ((x,x,y,y)(z,z,sq,sq)) so pk operands need no packing VALU.
__global__ __launch_bounds__(512) void argmm_kernel(
    const float* __restrict__ xyz,   // [NBATCH, NPTS, 3]
    int* __restrict__ pmax,          // [NBATCH*NPTS]
    int* __restrict__ pmin)          // [NBATCH*NPTS]
{
    __shared__ int smem[8192];               // 32 KB, phase-aliased
    // phase 1: float4 xyzD[1024]  (scaled, duplicated: 16 KB used)
    // phase 2: int mv[2048] | int mi[2048] | uns nv[2048] | int ni[2048]
    float4* xyzD = (float4*)smem;

    const int t  = threadIdx.x;
    const int bl = blockIdx.x >> 2;
    const int qq = blockIdx.x & 3;           // point-quarter of this block
    const float* xp = xyz + (size_t)bl * NPTS * 3;

    // stage all 512 points, scaled & duplicated; sq in ref order from raw
    {
        float x = xp[3 * t], y = xp[3 * t + 1], z = xp[3 * t + 2];
        float sq = (x * x + y * y) + z * z;  // matches np.sum(x*x,-1)
        float x2 = -2.0f * x, y2 = -2.0f * y, z2 = -2.0f * z;
        xyzD[2 * t]     = make_float4(x2, x2, y2, y2);
        xyzD[2 * t + 1] = make_float4(z2, z2, sq, sq);
    }

    // own 4 points RAW from global, packed as 2 v2f pairs
    const int g = t & 31, s = t >> 5;
    const int pbase = qq * 128 + g * 4;
    v2f ox2[2], oy2[2], oz2[2], oq2[2];
    {
        const float4* own = (const float4*)(xp + 3 * pbase);
        float4 o0 = own[0], o1 = own[1], o2 = own[2];
        ox2[0] = (v2f){o0.x, o0.w};  oy2[0] = (v2f){o0.y, o1.x};  oz2[0] = (v2f){o0.z, o1.y};
        ox2[1] = (v2f){o1.z, o2.y};  oy2[1] = (v2f){o1.w, o2.z};  oz2[1] = (v2f){o2.x, o2.w};
        #pragma unroll
        for (int j = 0; j < 2; ++j)
            oq2[j] = (ox2[j] * ox2[j] + oy2[j] * oy2[j]) + oz2[j] * oz2[j];
    }
    __syncthreads();

    const int mbase = s * 32;
    int bmax[4], ima[4], imi[4]; unsigned bmin[4];
    #pragma unroll
    for (int k = 0; k < 4; ++k) {
        bmax[k] = (int)0x80000000;           // INT_MIN
        bmin[k] = 0xFFFFFFFFu;
        ima[k] = mbase; imi[k] = mbase;
    }

    const v2f* xd = (const v2f*)xyzD;
    #pragma unroll 8
    for (int mm = 0; mm < 32; ++mm) {
        int m = mbase + mm;
        v2f qxx = xd[4 * m + 0];             // (x2,x2) — pk-ready, no packing
        v2f qyy = xd[4 * m + 1];             // (y2,y2)
        v2f qzz = xd[4 * m + 2];             // (z2,z2)
        v2f qss = xd[4 * m + 3];             // (sq,sq)
        #pragma unroll
        for (int j = 0; j < 2; ++j) {
            v2f dt = (ox2[j] * qxx + oy2[j] * qyy) + oz2[j] * qzz;  // == -2*dot
            v2f d2 = (oq2[j] + qss) + dt;    // bits == ref d2 (pre-clamp)
            int b0 = __float_as_int(d2.x);
            int b1 = __float_as_int(d2.y);
            const int k0 = 2 * j, k1 = 2 * j + 1;

            bool g0 = b0 > bmax[k0];         // strict -> first occurrence
            ima[k0] = g0 ? m : ima[k0];  bmax[k0] = g0 ? b0 : bmax[k0];
            unsigned u0 = (unsigned)b0 - 1u; // +0.0/neg -> never-wins
            bool l0 = u0 < bmin[k0];
            imi[k0] = l0 ? m : imi[k0];  bmin[k0] = l0 ? u0 : bmin[k0];

            bool g1 = b1 > bmax[k1];
            ima[k1] = g1 ? m : ima[k1];  bmax[k1] = g1 ? b1 : bmax[k1];
            unsigned u1 = (unsigned)b1 - 1u;
            bool l1 = u1 < bmin[k1];
            imi[k1] = l1 ? m : imi[k1];  bmin[k1] = l1 ? u1 : bmin[k1];
        }
    }
    __syncthreads();   // all xyzD reads done; safe to alias merge scratch

    int*      mv = smem;                     // [16][128]
    int*      mi = smem + 2048;
    unsigned* nv = (unsigned*)smem + 4096;
    int*      ni = smem + 6144;
    #pragma unroll
    for (int k = 0; k < 4; ++k) {
        int pt = g * 4 + k;
        mv[s * 128 + pt] = bmax[k];  mi[s * 128 + pt] = ima[k];
        nv[s * 128 + pt] = bmin[k];  ni[s * 128 + pt] = imi[k];
    }
    __syncthreads();

    // merge 16 ascending-m subranges; strict compare keeps lowest m-range on
    // exact ties -> first-occurrence. 128 threads max, 128 threads min.
    if (t < 256) {
        const int pt = t & 127;
        const int out_idx = bl * NPTS + qq * 128 + pt;
        if (t < 128) {
            int bv = mv[pt]; int bi = mi[pt];
            #pragma unroll
            for (int ss = 1; ss < 16; ++ss) {
                int v = mv[ss * 128 + pt]; int i = mi[ss * 128 + pt];
                bool w = v > bv; bi = w ? i : bi; bv = w ? v : bv;
            }
            pmax[out_idx] = bi;
        } else {
            unsigned sv = nv[pt]; int si = ni[pt];
            #pragma unroll
            for (int ss = 1; ss < 16; ++ss) {
                unsigned u = nv[ss * 128 + pt]; int j = ni[ss * 128 + pt];
                bool x = u < sv; si = x ? j : si; sv = x ? u : sv;
            }
            pmin[out_idx] = si;
        }
    }
}

// ---------------- K2: sim gathers, j-chunked, one barrier per block --------
// (R7-exact form — the measured best variant.)
// Grid 2048 = 256 batches x 8 chunks of 16 ypred rows. Block 512 thr: thread
// t owns point n=t; reads a once, gathers both partners. ypred read exactly
// once from HBM chip-wide -> streaming-bound.
__global__ __launch_bounds__(512) void sim_kernel(
    const float* __restrict__ ypred,   // [NBATCH, JDIM, NPTS]
    const int* __restrict__ pmax,
    const int* __restrict__ pmin,
    float* __restrict__ partials)      // [2048]
{
    __shared__ float L[16 * NPTS];     // 32 KB tile
    __shared__ float wred[8];

    const int t  = threadIdx.x;
    const int bl = blockIdx.x >> 3;
    const int c  = blockIdx.x & 7;     // j-chunk

    // partner indices: issue early, land under the staging loads
    const int pma = pmax[bl * NPTS + t];
    const int pmi = pmin[bl * NPTS + t];

    const float4* src = (const float4*)(ypred + (size_t)bl * JDIM * NPTS
                                              + (size_t)c * 16 * NPTS);
    float4 v0 = src[t], v1 = src[512 + t], v2 = src[1024 + t], v3 = src[1536 + t];
    float4* dst = (float4*)L;
    dst[t] = v0;  dst[512 + t] = v1;  dst[1024 + t] = v2;  dst[1536 + t] = v3;
    __syncthreads();

    float accP = 0.0f, accM = 0.0f;
    #pragma unroll
    for (int r = 0; r < 16; ++r) {
        float a  = L[r * NPTS + t];      // stride-1, conflict-free
        float b  = L[r * NPTS + pma];    // random gather, ~2-way avg
        float cm = L[r * NPTS + pmi];
        accP = fmaf(a, b, accP);
        accM = fmaf(a, cm, accM);
    }

    float d = accP - accM;
    #pragma unroll
    for (int off = 32; off > 0; off >>= 1)
        d += __shfl_down(d, off);
    if ((t & 63) == 0) wred[t >> 6] = d;
    __syncthreads();
    if (t == 0) {
        float ssum = 0.0f;
        #pragma unroll
        for (int w = 0; w < 8; ++w) ssum += wred[w];
        partials[blockIdx.x] = ssum;
    }
}

// ---------------- K3: final mean over 2048 partials -------------------------
__global__ __launch_bounds__(1024) void reduce_mean_kernel(
    const float* __restrict__ partials, float* __restrict__ out)
{
    const int t = threadIdx.x;
    float v = partials[t] + partials[t + 1024];
    #pragma unroll
    for (int off = 32; off > 0; off >>= 1)
        v += __shfl_down(v, off);

    __shared__ float w[16];
    if ((t & 63) == 0) w[t >> 6] = v;
    __syncthreads();
    if (t == 0) {
        float s = 0.0f;
        #pragma unroll
        for (int i = 0; i < 16; ++i) s += w[i];
        out[0] = s * (1.0f / (float)NPAIR);
    }
}

extern "C" void kernel_launch(void* const* d_in, const int* in_sizes, int n_in,
                              void* d_out, int out_size, void* d_ws, size_t ws_size,
                              hipStream_t stream) {
    const float* ypred = (const float*)d_in[0];   // [8,32,128,512] f32
    const float* xyz   = (const float*)d_in[1];   // [8,32,512,3]  f32

    // ws: pmax[131072] ints, pmin[131072] ints, partials[2048] floats (~1.06 MB)
    int*   pmax     = (int*)d_ws;
    int*   pmin     = pmax + NPAIR;
    float* partials = (float*)(pmin + NPAIR);
    float* out      = (float*)d_out;

    argmm_kernel<<<4 * NBATCH, 512, 0, stream>>>(xyz, pmax, pmin);
    sim_kernel<<<8 * NBATCH, 512, 0, stream>>>(ypred, pmax, pmin, partials);
    reduce_mean_kernel<<<1, 1024, 0, stream>>>(partials, out);
}